// Round 13
// baseline (158.067 us; speedup 1.0000x reference)
//
#include <hip/hip_runtime.h>

#define NN 100000
#define NE 1600000
#define D 64
#define BKT_SHIFT 7
#define BKT_NODES 128
#define BKT_MASK 127
#define NBKT 782            // ceil(NN / 128) buckets of 128 nodes (p2 side)
#define SRC_MASK 0x1FFFF    // src < 100000 < 2^17
#define EPB 8192            // edges per p2 block (196 blocks, 32 edges/thread)
#define NPB ((NE + EPB - 1) / EPB)   // 196
#define BINCAP 2560         // mean 2048, sd ~45 -> 11 sigma
#define HCAP 1600           // per-half sEdge capacity (mean 1024, ~12 sigma)
#define NT4 (NN / 4)        // 25000 4-row transform tiles (exact)
#define TGRID 2048          // dedicated transform blocks

// float -> bf16 (round-to-nearest-even; inputs finite)
__device__ __forceinline__ unsigned short f2bf(float f) {
    unsigned u = __float_as_uint(f);
    unsigned r = u + 0x7FFF + ((u >> 16) & 1);
    return (unsigned short)(r >> 16);
}

__device__ __forceinline__ int cmp4(const int4& v, int k) {
    return k == 0 ? v.x : k == 1 ? v.y : k == 2 ? v.z : v.w;
}

// wave-broadcast one lane's float to all lanes (v_readlane -> SGPR operand)
__device__ __forceinline__ float rl(float v, int sl) {
    return __uint_as_float(__builtin_amdgcn_readlane(__float_as_uint(v), sl));
}

// ---------------- seed: zero per-bucket counts -----------------------------
__global__ __launch_bounds__(256) void seed_cursor(int* __restrict__ cursor) {
    const int i = blockIdx.x * 256 + threadIdx.x;
    if (i < NBKT) cursor[i] = 0;
}

// ---------------- fused: p2 scatter (blocks < NPB) + transform (rest) ------
// p2: round-9 validated (782 bins).  transform v3: the LDS-staging version
// paid 64 broadcast ds_read_b128 per wave-tile (12cyc each — broadcast still
// moves 1KB to the register file for 16 useful bytes) = ~31us of LDS pipe
// chip-wide.  v3: one COALESCED global_load_dwordx4 per 4-row tile (lane i
// holds float4 #i — per-lane-distinct, unlike r11's uniform-addr mistake),
// then v_readlane broadcasts each element to SGPR feeding v_fmac directly.
// 512 VALU inst/tile -> ~10us floor; zero LDS, zero barriers; next-tile load
// software-pipelined.  FMA expression identical -> absmax stays 0.125.
__global__ __launch_bounds__(256) void fused_tp2(const float* __restrict__ feat,
                                                 const float* __restrict__ W,
                                                 unsigned short* __restrict__ hb,
                                                 const int* __restrict__ src,
                                                 const int* __restrict__ dst,
                                                 int* __restrict__ cursor,
                                                 int* __restrict__ binned) {
    __shared__ int hist[NBKT];           // p2 only
    const int t = threadIdx.x;

    if (blockIdx.x < NPB) {
        // ---------------- p2: 8192 edges, 32/thread ----------------
        for (int i = t; i < NBKT; i += 256) hist[i] = 0;
        __syncthreads();

        const int4* __restrict__ src4 = (const int4*)src;
        const int4* __restrict__ dst4 = (const int4*)dst;
        const int qlo = blockIdx.x * (EPB / 4);
        const int nq  = NE / 4;          // 400000, exact

        int4 dv[8];
        int  rk[8][4];
#pragma unroll
        for (int it = 0; it < 8; ++it) {
            const int idx = qlo + it * 256 + t;
            dv[it] = (idx < nq) ? dst4[idx] : make_int4(-1, -1, -1, -1);
        }
#pragma unroll
        for (int it = 0; it < 8; ++it)
#pragma unroll
            for (int k = 0; k < 4; ++k) {
                const int d = cmp4(dv[it], k);
                if (d >= 0) rk[it][k] = atomicAdd(&hist[d >> BKT_SHIFT], 1);
            }
        __syncthreads();

        // reserve global ranges; hist becomes base (packed cursors: hot L2
        // lines — padding them was a measured regression, round 1)
        for (int i = t; i < NBKT; i += 256) {
            const int c = hist[i];
            int base = i * BINCAP;
            if (c) base += atomicAdd(&cursor[i], c);
            hist[i] = base;
        }
        __syncthreads();

#pragma unroll
        for (int it = 0; it < 8; ++it) {
            const int idx = qlo + it * 256 + t;
            if (idx < nq) {
                const int4 s4 = src4[idx];
#pragma unroll
                for (int k = 0; k < 4; ++k) {
                    const int d = cmp4(dv[it], k);
                    const int s = cmp4(s4, k);
                    binned[hist[d >> BKT_SHIFT] + rk[it][k]] =
                        s | ((d & BKT_MASK) << 17);
                }
            }
        }
    } else {
        // ------- transform v3: coalesced load + readlane broadcast ---------
        const int bid  = blockIdx.x - NPB;
        const int lane = t & 63;
        const int wv   = t >> 6;
        float4 wreg[16];
        const float4* __restrict__ W4 = (const float4*)W;
#pragma unroll
        for (int i = 0; i < 16; ++i) wreg[i] = W4[lane * 16 + i];
        const float4* __restrict__ F4 = (const float4*)feat;

        const int wid  = bid * 4 + wv;   // global wave id, each wave independent
        const int wstr = TGRID * 4;      // 8192 waves

        int tcur = wid;
        if (tcur < NT4) {
            float4 cur = F4[(size_t)tcur * 64 + lane];   // 4 rows, coalesced
            for (;;) {
                const int tnxt = tcur + wstr;
                float4 nxt = make_float4(0.f, 0.f, 0.f, 0.f);
                if (tnxt < NT4) nxt = F4[(size_t)tnxt * 64 + lane];  // prefetch

                float a0 = 0.f, a1 = 0.f, a2 = 0.f, a3 = 0.f;
#pragma unroll
                for (int k4 = 0; k4 < 16; ++k4) {
                    const float4 w = wreg[k4];
                    a0 += rl(cur.x, k4)      * w.x + rl(cur.y, k4)      * w.y
                        + rl(cur.z, k4)      * w.z + rl(cur.w, k4)      * w.w;
                    a1 += rl(cur.x, 16 + k4) * w.x + rl(cur.y, 16 + k4) * w.y
                        + rl(cur.z, 16 + k4) * w.z + rl(cur.w, 16 + k4) * w.w;
                    a2 += rl(cur.x, 32 + k4) * w.x + rl(cur.y, 32 + k4) * w.y
                        + rl(cur.z, 32 + k4) * w.z + rl(cur.w, 32 + k4) * w.w;
                    a3 += rl(cur.x, 48 + k4) * w.x + rl(cur.y, 48 + k4) * w.y
                        + rl(cur.z, 48 + k4) * w.z + rl(cur.w, 48 + k4) * w.w;
                }
                const size_t ob = (size_t)tcur * 4 * D + lane;
                hb[ob]         = f2bf(a0);
                hb[ob + D]     = f2bf(a1);
                hb[ob + 2 * D] = f2bf(a2);
                hb[ob + 3 * D] = f2bf(a3);

                if (tnxt >= NT4) break;
                cur = nxt;
                tcur = tnxt;
            }
        }
    }
}

// ---------------- bucket_gather: half-bucket blocks (r12 validated) --------
__global__ __launch_bounds__(256) void bucket_gather(const uint2* __restrict__ hb2,
                                                     const int* __restrict__ binned,
                                                     const int* __restrict__ cursor,
                                                     const float* __restrict__ bias,
                                                     float4* __restrict__ out4) {
    __shared__ int cnt[64];
    __shared__ int pre[64];
    __shared__ int sEdge[HCAP];
    const int t = threadIdx.x;
    const int b = blockIdx.x >> 1;       // 128-node bucket
    const int h = blockIdx.x & 1;        // 64-node half
    if (t < 64) cnt[t] = 0;
    __syncthreads();

    const int gbase = b * BINCAP;
    int sz = cursor[b];
    if (sz > BINCAP) sz = BINCAP;    // 11-sigma guard

    // rank this half's edges per node (counting sort pass 1); filter bit 6
    int pk[10], dd[10], rr[10];      // BINCAP/256 == 10
#pragma unroll
    for (int it = 0; it < 10; ++it) {
        const int e = it * 256 + t;
        dd[it] = -1;
        if (e < sz) {
            const int p = binned[gbase + e];
            const int d7 = (p >> 17) & BKT_MASK;
            if ((d7 >> 6) == h) {
                dd[it] = d7 & 63;
                pk[it] = p & SRC_MASK;
                rr[it] = atomicAdd(&cnt[dd[it]], 1);
            }
        }
    }
    __syncthreads();

    // inclusive scan of cnt[64] inside wave 0
    if (t < 64) {
        int v = cnt[t];
#pragma unroll
        for (int s = 1; s < 64; s <<= 1) {
            const int u = __shfl_up(v, s);
            if (t >= s) v += u;
        }
        pre[t] = v;
    }
    __syncthreads();

    // scatter into per-node segments: node d owns [pre[d]-cnt[d], pre[d])
#pragma unroll
    for (int it = 0; it < 10; ++it) {
        if (dd[it] >= 0) {
            const int pos = pre[dd[it]] - cnt[dd[it]] + rr[it];
            if (pos < HCAP) sEdge[pos] = pk[it];   // 12-sigma guard
        }
    }
    __syncthreads();

    // accumulate: quarter-wave per node, 4 fp32 cols per lane, 8 loads in flight
    const int q  = t >> 4;           // 16 quarters; quarter q owns nodes q*4..q*4+3
    const int c4 = t & 15;           // 8-byte column group (4 bf16 cols)
    const float4 bv = ((const float4*)bias)[c4];
#pragma unroll
    for (int i = 0; i < 4; ++i) {
        const int n    = q * 4 + i;
        const int node = b * BKT_NODES + h * 64 + n;
        if (node >= NN) break;       // uniform within quarter
        int end = pre[n];
        if (end > HCAP) end = HCAP;
        int e = end - cnt[n];
        if (e < 0) e = 0;
        float ax = 0.f, ay = 0.f, az = 0.f, aw = 0.f;
        for (; e < end; e += 8) {
            uint2 x[8];
#pragma unroll
            for (int j = 0; j < 8; ++j) {
                const int idx = (e + j < end) ? sEdge[e + j] : -1;
                x[j] = (idx >= 0) ? hb2[(size_t)idx * 16 + c4] : make_uint2(0u, 0u);
            }
#pragma unroll
            for (int j = 0; j < 8; ++j) {
                ax += __uint_as_float(x[j].x << 16);
                ay += __uint_as_float(x[j].x & 0xFFFF0000u);
                az += __uint_as_float(x[j].y << 16);
                aw += __uint_as_float(x[j].y & 0xFFFF0000u);
            }
        }
        float4 v;
        v.x = ax + bv.x; v.y = ay + bv.y; v.z = az + bv.z; v.w = aw + bv.w;
        out4[(size_t)node * 16 + c4] = v;
    }
}

extern "C" void kernel_launch(void* const* d_in, const int* in_sizes, int n_in,
                              void* d_out, int out_size, void* d_ws, size_t ws_size,
                              hipStream_t stream) {
    const float* feat = (const float*)d_in[0];
    const int*   src  = (const int*)d_in[1];
    const int*   dst  = (const int*)d_in[2];
    const float* W    = (const float*)d_in[3];
    const float* bias = (const float*)d_in[4];
    float4* out = (float4*)d_out;

    // workspace layout (~20.8 MB)
    unsigned short* hb = (unsigned short*)d_ws;       // NN*D bf16 (12.8 MB)
    int* binned = (int*)(hb + (size_t)NN * D);        // NBKT*BINCAP (8.0 MB)
    int* cursor = binned + NBKT * BINCAP;             // NBKT counts

    seed_cursor<<<(NBKT + 255) / 256, 256, 0, stream>>>(cursor);
    fused_tp2<<<NPB + TGRID, 256, 0, stream>>>(feat, W, hb, src, dst, cursor, binned);
    bucket_gather<<<2 * NBKT, 256, 0, stream>>>((const uint2*)hb, binned, cursor,
                                                bias, out);
}